// Round 14
// baseline (132.299 us; speedup 1.0000x reference)
//
#include <hip/hip_runtime.h>
#include <stdint.h>

#define NTOK 8192
#define INF  4096
#define OUTF 4096
#define KDIM 4096
#define KB4  2048   // packed fp4 row bytes (2 elems/byte)

using i32x4 = __attribute__((ext_vector_type(4))) int;
using i32x8 = __attribute__((ext_vector_type(8))) int;
using f32x4 = __attribute__((ext_vector_type(4))) float;

#define GLOAD16(gp, lp) __builtin_amdgcn_global_load_lds( \
    (const __attribute__((address_space(1))) uint32_t*)(gp), \
    (__attribute__((address_space(3))) uint32_t*)(lp), 16, 0, 0)

#define SBARE()  do { __builtin_amdgcn_s_barrier(); __builtin_amdgcn_sched_barrier(0); } while (0)
#define VMCNT4() do { asm volatile("s_waitcnt vmcnt(4)" ::: "memory"); __builtin_amdgcn_sched_barrier(0); } while (0)
#define VMCNT0() do { asm volatile("s_waitcnt vmcnt(0)" ::: "memory"); __builtin_amdgcn_sched_barrier(0); } while (0)

// full-grid XCD swizzle (512 blocks, 8 XCDs)
__device__ __forceinline__ void full_swizzle(int orig, int& row0, int& col0) {
    const int wgid  = ((orig & 7) << 6) | (orig >> 3);
    const int chunk = wgid >> 6;
    const int c     = wgid & 63;
    row0 = ((chunk << 2) | (c & 3)) * 256;
    col0 = (c >> 2) * 256;
}

// ---------------- pack pass v4: 16 floats/thread, 4 loads in flight ---------
__device__ __forceinline__ unsigned int nib16(float4 v) {
    return (0x2u | ((v.x < 0.0f) ? 8u : 0u))
         | ((0x2u | ((v.y < 0.0f) ? 8u : 0u)) << 4)
         | ((0x2u | ((v.z < 0.0f) ? 8u : 0u)) << 8)
         | ((0x2u | ((v.w < 0.0f) ? 8u : 0u)) << 12);
}

__global__ void pack_fp4(const float* __restrict__ x, const float* __restrict__ w,
                         char* __restrict__ xp, char* __restrict__ wp,
                         int gx, int gtot) {
    int gtid = blockIdx.x * blockDim.x + threadIdx.x;
    int nthr = gridDim.x * blockDim.x;
    for (int g = gtid; g < gtot; g += nthr) {
        const float4* s;
        uint64_t* d;
        int gi;
        if (g < gx) { s = (const float4*)x; d = (uint64_t*)xp; gi = g; }
        else        { s = (const float4*)w; d = (uint64_t*)wp; gi = g - gx; }
        const float4* sp = s + (size_t)gi * 4;
        float4 v0 = sp[0];
        float4 v1 = sp[1];
        float4 v2 = sp[2];
        float4 v3 = sp[3];
        uint32_t lo = nib16(v0) | (nib16(v1) << 16);
        uint32_t hi = nib16(v2) | (nib16(v3) << 16);
        d[gi] = (uint64_t)lo | ((uint64_t)hi << 32);
    }
}

// ---------------- MX-FP4 MFMA GEMM, 256x256, 4-phase (R11/R13-proven core) --
// Unchanged compute/schedule. NEW: C-write uses nontemporal stores (nt) so
// the 134 MB output stream bypasses L3 — keeps x,w (201 MB) + packed (25 MB)
// L3-resident across graph replays, un-thrashing the pack pass's reads.
__global__ __launch_bounds__(512, 2) void bgemm_fp4(
        const char*  __restrict__ Xp,   // [NTOK][KB4] fp4-packed signs
        const char*  __restrict__ Wp,   // [OUTF][KB4]
        const float* __restrict__ bias, // [OUTF]
        float*       __restrict__ out)  // [NTOK][OUTF]
{
    __shared__ __align__(16) char As[2][32768];
    __shared__ __align__(16) char Bs[2][32768];

    const int tid  = threadIdx.x;
    const int lane = tid & 63;
    const int wid  = tid >> 6;
    const int wr   = wid >> 2;          // 0..1 (128-row half)
    const int wc   = wid & 3;           // 0..3 (64-col quarter)
    const int cl   = lane & 15;
    const int rg   = lane >> 4;

    int row0, col0;
    full_swizzle(blockIdx.x, row0, col0);

    const int rr     = tid >> 3;                       // 0..63
    const int colOff = ((tid & 7) << 4) ^ ((rr & 7) << 4);
    const char* gA = Xp + (size_t)(row0 + rr) * KB4 + colOff;
    const char* gB = Wp + (size_t)(col0 + rr) * KB4 + colOff;
    const int d0 = tid * 16;

#define STGF(arr, p, g, ktB) do { \
    GLOAD16((g) + (size_t)0   * KB4 + (ktB), &arr[p][d0]); \
    GLOAD16((g) + (size_t)64  * KB4 + (ktB), &arr[p][8192 + d0]); \
    GLOAD16((g) + (size_t)128 * KB4 + (ktB), &arr[p][16384 + d0]); \
    GLOAD16((g) + (size_t)192 * KB4 + (ktB), &arr[p][24576 + d0]); \
} while (0)

    const int aRow = (wr * 128 + cl) * 128;
    const int bRow = (wc * 64 + cl) * 128;
    const int kq0  = (rg << 4) ^ ((cl & 7) << 4);
    const int kq1  = kq0 ^ 64;

    f32x4 acc[8][4];
#pragma unroll
    for (int m = 0; m < 8; ++m)
#pragma unroll
        for (int n = 0; n < 4; ++n)
#pragma unroll
            for (int j = 0; j < 4; ++j) acc[m][n][j] = 0.0f;

    i32x4 af[4][2], bf[4][2];

#define LDA(p, MH) do { \
    _Pragma("unroll") for (int m = 0; m < 4; ++m) { \
        af[m][0] = *reinterpret_cast<const i32x4*>(&As[p][aRow + ((MH) * 4 + m) * 2048 + kq0]); \
        af[m][1] = *reinterpret_cast<const i32x4*>(&As[p][aRow + ((MH) * 4 + m) * 2048 + kq1]); \
    } } while (0)
#define LDBALL(p) do { \
    _Pragma("unroll") for (int n = 0; n < 4; ++n) { \
        bf[n][0] = *reinterpret_cast<const i32x4*>(&Bs[p][bRow + (n) * 2048 + kq0]); \
        bf[n][1] = *reinterpret_cast<const i32x4*>(&Bs[p][bRow + (n) * 2048 + kq1]); \
    } } while (0)
// kk outer so consecutive MFMAs hit different acc registers.
#define MMALL(MH) do { \
    __builtin_amdgcn_s_setprio(1); \
    _Pragma("unroll") for (int kk = 0; kk < 2; ++kk) \
    _Pragma("unroll") for (int m = 0; m < 4; ++m) \
    _Pragma("unroll") for (int n = 0; n < 4; ++n) { \
        i32x8 a8 = {af[m][kk][0], af[m][kk][1], af[m][kk][2], af[m][kk][3], 0, 0, 0, 0}; \
        i32x8 b8 = {bf[n][kk][0], bf[n][kk][1], bf[n][kk][2], bf[n][kk][3], 0, 0, 0, 0}; \
        acc[(MH) * 4 + m][n] = __builtin_amdgcn_mfma_scale_f32_16x16x128_f8f6f4( \
            a8, b8, acc[(MH) * 4 + m][n], 4, 4, 0, 0x7F7F7F7F, 0, 0x7F7F7F7F); \
    } \
    __builtin_amdgcn_s_setprio(0); \
} while (0)

    // ---- prologue: tile0 (A,B) + tile1 B = 12 gloads; retire tile0 --------
    STGF(As, 0, gA, 0);
    STGF(Bs, 0, gB, 0);
    STGF(Bs, 1, gB, 128);
    VMCNT4();
    SBARE();

    // ---- main loop: tile 2i (p0) ph0-1, tile 2i+1 (p1) ph2-3 --------------
    int kb = 0;  // = i*256 bytes
#pragma unroll 1
    for (int i = 0; i < 7; ++i, kb += 256) {
        // ph0: reads A(p0,MH0)+B(p0) ; stage A.p1(t+1) ; MFMA(MH0)
        LDA(0, 0); LDBALL(0);
        STGF(As, 1, gA, kb + 128);
        MMALL(0);
        SBARE();
        // ph1: reads A(p0,MH1) ; stage B.p0(t+2) ; MFMA(MH1) ; vmcnt(4)
        LDA(0, 1);
        STGF(Bs, 0, gB, kb + 256);
        MMALL(1);
        VMCNT4(); SBARE();
        // ph2: reads A(p1,MH0)+B(p1) ; stage A.p0(t+2) ; MFMA(MH0)
        LDA(1, 0); LDBALL(1);
        STGF(As, 0, gA, kb + 256);
        MMALL(0);
        SBARE();
        // ph3: reads A(p1,MH1) ; stage B.p1(t+3) ; MFMA(MH1) ; vmcnt(4)
        LDA(1, 1);
        STGF(Bs, 1, gB, kb + 384);
        MMALL(1);
        VMCNT4(); SBARE();
    }

    // ---- epilogue: stage A.p1 (tile15 @1920); drain; compute t14, t15 -----
    STGF(As, 1, gA, 1920);
    VMCNT0();
    SBARE();
    LDA(0, 0); LDBALL(0); MMALL(0);
    LDA(0, 1);            MMALL(1);
    LDA(1, 0); LDBALL(1); MMALL(0);
    LDA(1, 1);            MMALL(1);

    // ---- C write: nontemporal (bypass L3); layout col=lane&15, row=rg*4+j -
    float bv[4];
#pragma unroll
    for (int n = 0; n < 4; ++n) bv[n] = bias[col0 + wc * 64 + n * 16 + cl];

#pragma unroll
    for (int m = 0; m < 8; ++m) {
        int rowbase = row0 + wr * 128 + m * 16 + rg * 4;
#pragma unroll
        for (int j = 0; j < 4; ++j) {
            size_t rb = (size_t)(rowbase + j) * OUTF;
#pragma unroll
            for (int n = 0; n < 4; ++n) {
                int col = col0 + wc * 64 + n * 16 + cl;
                __builtin_nontemporal_store(acc[m][n][j] + bv[n], &out[rb + col]);
            }
        }
    }
#undef STGF
#undef LDA
#undef LDBALL
#undef MMALL
}

// ================= i8 path (R7 core, verified) — ws fallback ================
__global__ void pack_i8(const float* __restrict__ x, const float* __restrict__ w,
                        char* __restrict__ xp, char* __restrict__ wp,
                        int gx, int gtot) {
    int gtid = blockIdx.x * blockDim.x + threadIdx.x;
    int nthr = gridDim.x * blockDim.x;
    for (int g = gtid; g < gtot; g += nthr) {
        const float* src;
        char* dst;
        int gi;
        if (g < gx) { src = x; dst = xp; gi = g; }
        else        { src = w; dst = wp; gi = g - gx; }
        const float4* s4 = reinterpret_cast<const float4*>(src + (size_t)gi * 16);
        int words[4];
#pragma unroll
        for (int q = 0; q < 4; ++q) {
            float4 v = s4[q];
            int b0 = (v.x < 0.0f) ? 0xFF : 0x01;
            int b1 = (v.y < 0.0f) ? 0xFF : 0x01;
            int b2 = (v.z < 0.0f) ? 0xFF : 0x01;
            int b3 = (v.w < 0.0f) ? 0xFF : 0x01;
            words[q] = b0 | (b1 << 8) | (b2 << 16) | (b3 << 24);
        }
        int4 o = make_int4(words[0], words[1], words[2], words[3]);
        *reinterpret_cast<int4*>(dst + (size_t)gi * 16) = o;
    }
}

__global__ __launch_bounds__(512, 2) void bgemm_i8_4ph(
        const char*  __restrict__ Xp, const char* __restrict__ Wp,
        const float* __restrict__ bias, float* __restrict__ out)
{
    __shared__ __align__(16) char As[2][32768];
    __shared__ __align__(16) char Bs[2][32768];

    const int tid  = threadIdx.x;
    const int lane = tid & 63;
    const int wid  = tid >> 6;
    const int wr   = wid >> 2;
    const int wc   = wid & 3;
    const int cl   = lane & 15;
    const int rg   = lane >> 4;

    int row0, col0;
    full_swizzle(blockIdx.x, row0, col0);

    const int rr     = tid >> 3;
    const int colOff = ((tid & 7) << 4) ^ ((rr & 7) << 4);
    const char* gA = Xp + (size_t)(row0 + rr) * KDIM + colOff;
    const char* gB = Wp + (size_t)(col0 + rr) * KDIM + colOff;
    const int d0 = tid * 16;

#define STGF(arr, p, g, ktB) do { \
    GLOAD16((g) + (size_t)0   * KDIM + (ktB), &arr[p][d0]); \
    GLOAD16((g) + (size_t)64  * KDIM + (ktB), &arr[p][8192 + d0]); \
    GLOAD16((g) + (size_t)128 * KDIM + (ktB), &arr[p][16384 + d0]); \
    GLOAD16((g) + (size_t)192 * KDIM + (ktB), &arr[p][24576 + d0]); \
} while (0)

    const int aRow = (wr * 128 + cl) * 128;
    const int bRow = (wc * 64 + cl) * 128;
    const int kq0  = (rg << 4) ^ ((cl & 7) << 4);
    const int kq1  = kq0 ^ 64;

    i32x4 acc[8][4];
#pragma unroll
    for (int m = 0; m < 8; ++m)
#pragma unroll
        for (int n = 0; n < 4; ++n)
#pragma unroll
            for (int j = 0; j < 4; ++j) acc[m][n][j] = 0;

    i32x4 af[4][2], bf[4][2];

#define LDA(p, MH) do { \
    _Pragma("unroll") for (int m = 0; m < 4; ++m) { \
        af[m][0] = *reinterpret_cast<const i32x4*>(&As[p][aRow + ((MH) * 4 + m) * 2048 + kq0]); \
        af[m][1] = *reinterpret_cast<const i32x4*>(&As[p][aRow + ((MH) * 4 + m) * 2048 + kq1]); \
    } } while (0)
#define LDBALL(p) do { \
    _Pragma("unroll") for (int n = 0; n < 4; ++n) { \
        bf[n][0] = *reinterpret_cast<const i32x4*>(&Bs[p][bRow + (n) * 2048 + kq0]); \
        bf[n][1] = *reinterpret_cast<const i32x4*>(&Bs[p][bRow + (n) * 2048 + kq1]); \
    } } while (0)
#define MMALL(MH) do { \
    __builtin_amdgcn_s_setprio(1); \
    _Pragma("unroll") for (int m = 0; m < 4; ++m) \
    _Pragma("unroll") for (int n = 0; n < 4; ++n) \
    _Pragma("unroll") for (int kk = 0; kk < 2; ++kk) \
        acc[(MH) * 4 + m][n] = __builtin_amdgcn_mfma_i32_16x16x64_i8( \
            af[m][kk], bf[n][kk], acc[(MH) * 4 + m][n], 0, 0, 0); \
    __builtin_amdgcn_s_setprio(0); \
} while (0)

    STGF(As, 0, gA, 0);
    STGF(Bs, 0, gB, 0);
    STGF(Bs, 1, gB, 128);
    VMCNT4();
    SBARE();

    int kb = 0;
#pragma unroll 1
    for (int i = 0; i < 15; ++i, kb += 256) {
        LDA(0, 0); LDBALL(0);
        STGF(As, 1, gA, kb + 128);
        MMALL(0);
        SBARE();
        LDA(0, 1);
        STGF(Bs, 0, gB, kb + 256);
        MMALL(1);
        VMCNT4(); SBARE();
        LDA(1, 0); LDBALL(1);
        STGF(As, 0, gA, kb + 256);
        MMALL(0);
        SBARE();
        LDA(1, 1);
        STGF(Bs, 1, gB, kb + 384);
        MMALL(1);
        VMCNT4(); SBARE();
    }

    STGF(As, 1, gA, 3968);
    VMCNT0();
    SBARE();
    LDA(0, 0); LDBALL(0); MMALL(0);
    LDA(0, 1);            MMALL(1);
    LDA(1, 0); LDBALL(1); MMALL(0);
    LDA(1, 1);            MMALL(1);

    float bv[4];
#pragma unroll
    for (int n = 0; n < 4; ++n) bv[n] = bias[col0 + wc * 64 + n * 16 + cl];

#pragma unroll
    for (int m = 0; m < 8; ++m) {
        int rowbase = row0 + wr * 128 + m * 16 + rg * 4;
#pragma unroll
        for (int j = 0; j < 4; ++j) {
            size_t rb = (size_t)(rowbase + j) * OUTF;
#pragma unroll
            for (int n = 0; n < 4; ++n) {
                int col = col0 + wc * 64 + n * 16 + cl;
                out[rb + col] = (float)acc[m][n][j] + bv[n];
            }
        }
    }
#undef STGF
#undef LDA
#undef LDBALL
#undef MMALL
}

// ================= popcount fallback (round-1, known-good) ==================
#define KW   64
#define LSTRIDE 66

__global__ void pack_both_fb(const float* __restrict__ x, const float* __restrict__ w,
                             uint64_t* __restrict__ xp, uint64_t* __restrict__ wp,
                             int nx, int ntot) {
    int gtid  = blockIdx.x * blockDim.x + threadIdx.x;
    int lane  = threadIdx.x & 63;
    int wave  = gtid >> 6;
    int nwaves = (gridDim.x * blockDim.x) >> 6;
    for (int q = wave; q < ntot; q += nwaves) {
        const float* src; uint64_t* dst; int qi;
        if (q < nx) { src = x; dst = xp; qi = q; }
        else        { src = w; dst = wp; qi = q - nx; }
        float v = src[(size_t)qi * 64 + lane];
        unsigned long long m = __ballot(v < 0.0f);
        if (lane == 0) dst[qi] = (uint64_t)m;
    }
}

__global__ __launch_bounds__(512, 2) void bgemm_popc_fb(
        const uint64_t* __restrict__ xp, const uint64_t* __restrict__ wp,
        const float* __restrict__ bias, float* __restrict__ out)
{
    __shared__ uint64_t xs[128 * LSTRIDE];
    __shared__ uint64_t ws[128 * LSTRIDE];
    const int tid  = threadIdx.x;
    const int row0 = blockIdx.y * 128;
    const int col0 = blockIdx.x * 128;
    {
        const uint64_t* xg = xp + (size_t)row0 * KW;
        const uint64_t* wg = wp + (size_t)col0 * KW;
#pragma unroll
        for (int m = 0; m < 8; ++m) {
            int q = (m * 512 + tid) * 2;
            int r = q >> 6;
            int k = q & 63;
            ulonglong2 vx = *reinterpret_cast<const ulonglong2*>(xg + q);
            xs[r * LSTRIDE + k] = vx.x; xs[r * LSTRIDE + k + 1] = vx.y;
            ulonglong2 vw = *reinterpret_cast<const ulonglong2*>(wg + q);
            ws[r * LSTRIDE + k] = vw.x; ws[r * LSTRIDE + k + 1] = vw.y;
        }
    }
    __syncthreads();
    const int tx = tid & 15;
    const int ty = tid >> 4;
    int acc[4][8];
#pragma unroll
    for (int i = 0; i < 4; ++i)
#pragma unroll
        for (int j = 0; j < 8; ++j) acc[i][j] = 0;
    const uint64_t* xrow = xs + ty * 4 * LSTRIDE;
    const uint64_t* wrow = ws + tx * LSTRIDE;
#pragma unroll 4
    for (int kk = 0; kk < KW; kk += 2) {
        ulonglong2 a[4]; ulonglong2 b[8];
#pragma unroll
        for (int i = 0; i < 4; ++i)
            a[i] = *reinterpret_cast<const ulonglong2*>(xrow + i * LSTRIDE + kk);
#pragma unroll
        for (int j = 0; j < 8; ++j)
            b[j] = *reinterpret_cast<const ulonglong2*>(wrow + j * 16 * LSTRIDE + kk);
#pragma unroll
        for (int i = 0; i < 4; ++i)
#pragma unroll
            for (int j = 0; j < 8; ++j)
                acc[i][j] += __builtin_popcountll(a[i].x ^ b[j].x)
                           + __builtin_popcountll(a[i].y ^ b[j].y);
    }
    float bcol[8];
#pragma unroll
    for (int j = 0; j < 8; ++j) bcol[j] = bias[col0 + tx + 16 * j];
#pragma unroll
    for (int i = 0; i < 4; ++i) {
        size_t r = (size_t)(row0 + ty * 4 + i);
#pragma unroll
        for (int j = 0; j < 8; ++j) {
            int c = col0 + tx + 16 * j;
            out[r * OUTF + c] = (float)(INF - 2 * acc[i][j]) + bcol[j];
        }
    }
}
// ============================================================================

extern "C" void kernel_launch(void* const* d_in, const int* in_sizes, int n_in,
                              void* d_out, int out_size, void* d_ws, size_t ws_size,
                              hipStream_t stream) {
    const float* x    = (const float*)d_in[0];
    const float* w    = (const float*)d_in[1];
    const float* bias = (const float*)d_in[2];
    float* out = (float*)d_out;

    const size_t need4 = (size_t)NTOK * KB4 + (size_t)OUTF * KB4;   // 25.2 MB
    const size_t need8 = (size_t)NTOK * KDIM + (size_t)OUTF * KDIM; // 50.3 MB

    if (ws_size >= need4) {
        char* xp = (char*)d_ws;
        char* wp = xp + (size_t)NTOK * KB4;
        const int gx   = NTOK * KDIM / 16;                // 2097152 (16-float tasks)
        const int gtot = gx + OUTF * KDIM / 16;           // 3145728
        pack_fp4<<<2048, 256, 0, stream>>>(x, w, xp, wp, gx, gtot);
        bgemm_fp4<<<512, 512, 0, stream>>>(xp, wp, bias, out);
    } else if (ws_size >= need8) {
        char* xp = (char*)d_ws;
        char* wp = xp + (size_t)NTOK * KDIM;
        const int gx   = NTOK * KDIM / 16;
        const int gtot = gx + OUTF * KDIM / 16;
        pack_i8<<<2048, 256, 0, stream>>>(x, w, xp, wp, gx, gtot);
        bgemm_i8_4ph<<<512, 512, 0, stream>>>(xp, wp, bias, out);
    } else {
        uint64_t* xp = (uint64_t*)d_ws;
        uint64_t* wp = xp + (size_t)NTOK * KW;
        const int nx   = NTOK * KW;
        const int ntot = nx + OUTF * KW;
        pack_both_fb<<<2048, 256, 0, stream>>>(x, w, xp, wp, nx, ntot);
        dim3 grid(OUTF / 128, NTOK / 128);
        bgemm_popc_fb<<<grid, 512, 0, stream>>>(xp, wp, bias, out);
    }
}

// Round 16
// 120.757 us; speedup vs baseline: 1.0956x; 1.0956x over previous
//
#include <hip/hip_runtime.h>
#include <stdint.h>

#define NTOK 8192
#define INF  4096
#define OUTF 4096
#define KDIM 4096
#define KB4  2048   // packed fp4 row bytes (2 elems/byte)

using i32x4 = __attribute__((ext_vector_type(4))) int;
using i32x8 = __attribute__((ext_vector_type(8))) int;
using f32x4 = __attribute__((ext_vector_type(4))) float;

#define GLOAD16(gp, lp) __builtin_amdgcn_global_load_lds( \
    (const __attribute__((address_space(1))) uint32_t*)(gp), \
    (__attribute__((address_space(3))) uint32_t*)(lp), 16, 0, 0)

#define SBARE()  do { __builtin_amdgcn_s_barrier(); __builtin_amdgcn_sched_barrier(0); } while (0)
#define VMCNT4() do { asm volatile("s_waitcnt vmcnt(4)" ::: "memory"); __builtin_amdgcn_sched_barrier(0); } while (0)
#define VMCNT0() do { asm volatile("s_waitcnt vmcnt(0)" ::: "memory"); __builtin_amdgcn_sched_barrier(0); } while (0)

// full-grid XCD swizzle (512 blocks, 8 XCDs)
__device__ __forceinline__ void full_swizzle(int orig, int& row0, int& col0) {
    const int wgid  = ((orig & 7) << 6) | (orig >> 3);
    const int chunk = wgid >> 6;
    const int c     = wgid & 63;
    row0 = ((chunk << 2) | (c & 3)) * 256;
    col0 = (c >> 2) * 256;
}

// ---------------- pack pass v4: 16 floats/thread, 4 loads in flight ---------
__device__ __forceinline__ unsigned int nib16(float4 v) {
    return (0x2u | ((v.x < 0.0f) ? 8u : 0u))
         | ((0x2u | ((v.y < 0.0f) ? 8u : 0u)) << 4)
         | ((0x2u | ((v.z < 0.0f) ? 8u : 0u)) << 8)
         | ((0x2u | ((v.w < 0.0f) ? 8u : 0u)) << 12);
}

__global__ void pack_fp4(const float* __restrict__ x, const float* __restrict__ w,
                         char* __restrict__ xp, char* __restrict__ wp,
                         int gx, int gtot) {
    int gtid = blockIdx.x * blockDim.x + threadIdx.x;
    int nthr = gridDim.x * blockDim.x;
    for (int g = gtid; g < gtot; g += nthr) {
        const float4* s;
        uint64_t* d;
        int gi;
        if (g < gx) { s = (const float4*)x; d = (uint64_t*)xp; gi = g; }
        else        { s = (const float4*)w; d = (uint64_t*)wp; gi = g - gx; }
        const float4* sp = s + (size_t)gi * 4;
        float4 v0 = sp[0];
        float4 v1 = sp[1];
        float4 v2 = sp[2];
        float4 v3 = sp[3];
        uint32_t lo = nib16(v0) | (nib16(v1) << 16);
        uint32_t hi = nib16(v2) | (nib16(v3) << 16);
        d[gi] = (uint64_t)lo | ((uint64_t)hi << 32);
    }
}

// ---------------- MX-FP4 MFMA GEMM, 256x256, 4-phase + LDS-transpose epi ----
// Compute/schedule = R13-proven core (absmax 0). Epilogue: acc -> LDS
// (free after K-loop) -> f32x4/lane read-back -> nontemporal full-line
// stores (wave covers 1024B contiguous = 8 full 128B lines). Output stream
// bypasses L3 without partial-line RMW; x,w stay L3-resident for pack.
__global__ __launch_bounds__(512, 2) void bgemm_fp4(
        const char*  __restrict__ Xp,   // [NTOK][KB4] fp4-packed signs
        const char*  __restrict__ Wp,   // [OUTF][KB4]
        const float* __restrict__ bias, // [OUTF]
        float*       __restrict__ out)  // [NTOK][OUTF]
{
    __shared__ __align__(16) char smem[131072];
#define ASm(p) (smem + ((p) << 15))
#define BSm(p) (smem + 65536 + ((p) << 15))

    const int tid  = threadIdx.x;
    const int lane = tid & 63;
    const int wid  = tid >> 6;
    const int wr   = wid >> 2;          // 0..1 (128-row half)
    const int wc   = wid & 3;           // 0..3 (64-col quarter)
    const int cl   = lane & 15;
    const int rg   = lane >> 4;

    int row0, col0;
    full_swizzle(blockIdx.x, row0, col0);

    const int rr     = tid >> 3;                       // 0..63
    const int colOff = ((tid & 7) << 4) ^ ((rr & 7) << 4);
    const char* gA = Xp + (size_t)(row0 + rr) * KB4 + colOff;
    const char* gB = Wp + (size_t)(col0 + rr) * KB4 + colOff;
    const int d0 = tid * 16;

#define STGF(base, g, ktB) do { \
    GLOAD16((g) + (size_t)0   * KB4 + (ktB), (base) + d0); \
    GLOAD16((g) + (size_t)64  * KB4 + (ktB), (base) + 8192 + d0); \
    GLOAD16((g) + (size_t)128 * KB4 + (ktB), (base) + 16384 + d0); \
    GLOAD16((g) + (size_t)192 * KB4 + (ktB), (base) + 24576 + d0); \
} while (0)

    const int aRow = (wr * 128 + cl) * 128;
    const int bRow = (wc * 64 + cl) * 128;
    const int kq0  = (rg << 4) ^ ((cl & 7) << 4);
    const int kq1  = kq0 ^ 64;

    f32x4 acc[8][4];
#pragma unroll
    for (int m = 0; m < 8; ++m)
#pragma unroll
        for (int n = 0; n < 4; ++n)
#pragma unroll
            for (int j = 0; j < 4; ++j) acc[m][n][j] = 0.0f;

    i32x4 af[4][2], bf[4][2];

#define LDA(p, MH) do { \
    _Pragma("unroll") for (int m = 0; m < 4; ++m) { \
        af[m][0] = *reinterpret_cast<const i32x4*>(ASm(p) + aRow + ((MH) * 4 + m) * 2048 + kq0); \
        af[m][1] = *reinterpret_cast<const i32x4*>(ASm(p) + aRow + ((MH) * 4 + m) * 2048 + kq1); \
    } } while (0)
#define LDBALL(p) do { \
    _Pragma("unroll") for (int n = 0; n < 4; ++n) { \
        bf[n][0] = *reinterpret_cast<const i32x4*>(BSm(p) + bRow + (n) * 2048 + kq0); \
        bf[n][1] = *reinterpret_cast<const i32x4*>(BSm(p) + bRow + (n) * 2048 + kq1); \
    } } while (0)
// kk outer so consecutive MFMAs hit different acc registers.
#define MMALL(MH) do { \
    __builtin_amdgcn_s_setprio(1); \
    _Pragma("unroll") for (int kk = 0; kk < 2; ++kk) \
    _Pragma("unroll") for (int m = 0; m < 4; ++m) \
    _Pragma("unroll") for (int n = 0; n < 4; ++n) { \
        i32x8 a8 = {af[m][kk][0], af[m][kk][1], af[m][kk][2], af[m][kk][3], 0, 0, 0, 0}; \
        i32x8 b8 = {bf[n][kk][0], bf[n][kk][1], bf[n][kk][2], bf[n][kk][3], 0, 0, 0, 0}; \
        acc[(MH) * 4 + m][n] = __builtin_amdgcn_mfma_scale_f32_16x16x128_f8f6f4( \
            a8, b8, acc[(MH) * 4 + m][n], 4, 4, 0, 0x7F7F7F7F, 0, 0x7F7F7F7F); \
    } \
    __builtin_amdgcn_s_setprio(0); \
} while (0)

    // ---- prologue: tile0 (A,B) + tile1 B = 12 gloads; retire tile0 --------
    STGF(ASm(0), gA, 0);
    STGF(BSm(0), gB, 0);
    STGF(BSm(1), gB, 128);
    VMCNT4();
    SBARE();

    // ---- main loop: tile 2i (p0) ph0-1, tile 2i+1 (p1) ph2-3 --------------
    int kb = 0;  // = i*256 bytes
#pragma unroll 1
    for (int i = 0; i < 7; ++i, kb += 256) {
        // ph0: reads A(p0,MH0)+B(p0) ; stage A.p1(t+1) ; MFMA(MH0)
        LDA(0, 0); LDBALL(0);
        STGF(ASm(1), gA, kb + 128);
        MMALL(0);
        SBARE();
        // ph1: reads A(p0,MH1) ; stage B.p0(t+2) ; MFMA(MH1) ; vmcnt(4)
        LDA(0, 1);
        STGF(BSm(0), gB, kb + 256);
        MMALL(1);
        VMCNT4(); SBARE();
        // ph2: reads A(p1,MH0)+B(p1) ; stage A.p0(t+2) ; MFMA(MH0)
        LDA(1, 0); LDBALL(1);
        STGF(ASm(0), gA, kb + 256);
        MMALL(0);
        SBARE();
        // ph3: reads A(p1,MH1) ; stage B.p1(t+3) ; MFMA(MH1) ; vmcnt(4)
        LDA(1, 1);
        STGF(BSm(1), gB, kb + 384);
        MMALL(1);
        VMCNT4(); SBARE();
    }

    // ---- K-epilogue: stage A.p1 (tile15 @1920); drain; compute t14, t15 ---
    STGF(ASm(1), gA, 1920);
    VMCNT0();
    SBARE();
    LDA(0, 0); LDBALL(0); MMALL(0);
    LDA(0, 1);            MMALL(1);
    LDA(1, 0); LDBALL(1); MMALL(0);
    LDA(1, 1);            MMALL(1);

    // ---- C-epilogue: acc -> LDS -> f32x4 nt stores (full 128B lines) ------
    // All waves' ds_reads are consumed (MFMAs issued) before this barrier.
    __syncthreads();
    float* lds_c = (float*)smem;        // 128 rows x 256 cols fp32 = 128 KB

    float bv[4];
#pragma unroll
    for (int n = 0; n < 4; ++n) bv[n] = bias[col0 + wc * 64 + n * 16 + cl];

#pragma unroll 1
    for (int ch = 0; ch < 2; ++ch) {
        if (wr == ch) {                 // waves owning rows [ch*128, ch*128+128)
#pragma unroll
            for (int m = 0; m < 8; ++m)
#pragma unroll
                for (int j = 0; j < 4; ++j) {
                    int r = m * 16 + rg * 4 + j;
#pragma unroll
                    for (int n = 0; n < 4; ++n)
                        lds_c[r * 256 + wc * 64 + n * 16 + cl] = acc[m][n][j] + bv[n];
                }
        }
        __syncthreads();
        // read back: wave covers one full 1KB row per instruction; lane = 16B
#pragma unroll
        for (int i = 0; i < 16; ++i) {
            int r = wid * 16 + i;
            f32x4 v = *reinterpret_cast<const f32x4*>(&lds_c[r * 256 + lane * 4]);
            size_t grow = (size_t)(row0 + ch * 128 + r);
            __builtin_nontemporal_store(v,
                reinterpret_cast<f32x4*>(&out[grow * OUTF + col0 + lane * 4]));
        }
        __syncthreads();
    }
#undef STGF
#undef LDA
#undef LDBALL
#undef MMALL
#undef ASm
#undef BSm
}

// ================= i8 path (R7 core, verified) — ws fallback ================
__global__ void pack_i8(const float* __restrict__ x, const float* __restrict__ w,
                        char* __restrict__ xp, char* __restrict__ wp,
                        int gx, int gtot) {
    int gtid = blockIdx.x * blockDim.x + threadIdx.x;
    int nthr = gridDim.x * blockDim.x;
    for (int g = gtid; g < gtot; g += nthr) {
        const float* src;
        char* dst;
        int gi;
        if (g < gx) { src = x; dst = xp; gi = g; }
        else        { src = w; dst = wp; gi = g - gx; }
        const float4* s4 = reinterpret_cast<const float4*>(src + (size_t)gi * 16);
        int words[4];
#pragma unroll
        for (int q = 0; q < 4; ++q) {
            float4 v = s4[q];
            int b0 = (v.x < 0.0f) ? 0xFF : 0x01;
            int b1 = (v.y < 0.0f) ? 0xFF : 0x01;
            int b2 = (v.z < 0.0f) ? 0xFF : 0x01;
            int b3 = (v.w < 0.0f) ? 0xFF : 0x01;
            words[q] = b0 | (b1 << 8) | (b2 << 16) | (b3 << 24);
        }
        int4 o = make_int4(words[0], words[1], words[2], words[3]);
        *reinterpret_cast<int4*>(dst + (size_t)gi * 16) = o;
    }
}

__global__ __launch_bounds__(512, 2) void bgemm_i8_4ph(
        const char*  __restrict__ Xp, const char* __restrict__ Wp,
        const float* __restrict__ bias, float* __restrict__ out)
{
    __shared__ __align__(16) char As[2][32768];
    __shared__ __align__(16) char Bs[2][32768];

    const int tid  = threadIdx.x;
    const int lane = tid & 63;
    const int wid  = tid >> 6;
    const int wr   = wid >> 2;
    const int wc   = wid & 3;
    const int cl   = lane & 15;
    const int rg   = lane >> 4;

    int row0, col0;
    full_swizzle(blockIdx.x, row0, col0);

    const int rr     = tid >> 3;
    const int colOff = ((tid & 7) << 4) ^ ((rr & 7) << 4);
    const char* gA = Xp + (size_t)(row0 + rr) * KDIM + colOff;
    const char* gB = Wp + (size_t)(col0 + rr) * KDIM + colOff;
    const int d0 = tid * 16;

#define STGF(arr, p, g, ktB) do { \
    GLOAD16((g) + (size_t)0   * KDIM + (ktB), &arr[p][d0]); \
    GLOAD16((g) + (size_t)64  * KDIM + (ktB), &arr[p][8192 + d0]); \
    GLOAD16((g) + (size_t)128 * KDIM + (ktB), &arr[p][16384 + d0]); \
    GLOAD16((g) + (size_t)192 * KDIM + (ktB), &arr[p][24576 + d0]); \
} while (0)

    const int aRow = (wr * 128 + cl) * 128;
    const int bRow = (wc * 64 + cl) * 128;
    const int kq0  = (rg << 4) ^ ((cl & 7) << 4);
    const int kq1  = kq0 ^ 64;

    i32x4 acc[8][4];
#pragma unroll
    for (int m = 0; m < 8; ++m)
#pragma unroll
        for (int n = 0; n < 4; ++n)
#pragma unroll
            for (int j = 0; j < 4; ++j) acc[m][n][j] = 0;

    i32x4 af[4][2], bf[4][2];

#define LDA(p, MH) do { \
    _Pragma("unroll") for (int m = 0; m < 4; ++m) { \
        af[m][0] = *reinterpret_cast<const i32x4*>(&As[p][aRow + ((MH) * 4 + m) * 2048 + kq0]); \
        af[m][1] = *reinterpret_cast<const i32x4*>(&As[p][aRow + ((MH) * 4 + m) * 2048 + kq1]); \
    } } while (0)
#define LDBALL(p) do { \
    _Pragma("unroll") for (int n = 0; n < 4; ++n) { \
        bf[n][0] = *reinterpret_cast<const i32x4*>(&Bs[p][bRow + (n) * 2048 + kq0]); \
        bf[n][1] = *reinterpret_cast<const i32x4*>(&Bs[p][bRow + (n) * 2048 + kq1]); \
    } } while (0)
#define MMALL(MH) do { \
    __builtin_amdgcn_s_setprio(1); \
    _Pragma("unroll") for (int m = 0; m < 4; ++m) \
    _Pragma("unroll") for (int n = 0; n < 4; ++n) \
    _Pragma("unroll") for (int kk = 0; kk < 2; ++kk) \
        acc[(MH) * 4 + m][n] = __builtin_amdgcn_mfma_i32_16x16x64_i8( \
            af[m][kk], bf[n][kk], acc[(MH) * 4 + m][n], 0, 0, 0); \
    __builtin_amdgcn_s_setprio(0); \
} while (0)

    STGF(As, 0, gA, 0);
    STGF(Bs, 0, gB, 0);
    STGF(Bs, 1, gB, 128);
    VMCNT4();
    SBARE();

    int kb = 0;
#pragma unroll 1
    for (int i = 0; i < 15; ++i, kb += 256) {
        LDA(0, 0); LDBALL(0);
        STGF(As, 1, gA, kb + 128);
        MMALL(0);
        SBARE();
        LDA(0, 1);
        STGF(Bs, 0, gB, kb + 256);
        MMALL(1);
        VMCNT4(); SBARE();
        LDA(1, 0); LDBALL(1);
        STGF(As, 0, gA, kb + 256);
        MMALL(0);
        SBARE();
        LDA(1, 1);
        STGF(Bs, 1, gB, kb + 384);
        MMALL(1);
        VMCNT4(); SBARE();
    }

    STGF(As, 1, gA, 3968);
    VMCNT0();
    SBARE();
    LDA(0, 0); LDBALL(0); MMALL(0);
    LDA(0, 1);            MMALL(1);
    LDA(1, 0); LDBALL(1); MMALL(0);
    LDA(1, 1);            MMALL(1);

    float bv[4];
#pragma unroll
    for (int n = 0; n < 4; ++n) bv[n] = bias[col0 + wc * 64 + n * 16 + cl];

#pragma unroll
    for (int m = 0; m < 8; ++m) {
        int rowbase = row0 + wr * 128 + m * 16 + rg * 4;
#pragma unroll
        for (int j = 0; j < 4; ++j) {
            size_t rb = (size_t)(rowbase + j) * OUTF;
#pragma unroll
            for (int n = 0; n < 4; ++n) {
                int col = col0 + wc * 64 + n * 16 + cl;
                out[rb + col] = (float)acc[m][n][j] + bv[n];
            }
        }
    }
#undef STGF
#undef LDA
#undef LDBALL
#undef MMALL
}

// ================= popcount fallback (round-1, known-good) ==================
#define KW   64
#define LSTRIDE 66

__global__ void pack_both_fb(const float* __restrict__ x, const float* __restrict__ w,
                             uint64_t* __restrict__ xp, uint64_t* __restrict__ wp,
                             int nx, int ntot) {
    int gtid  = blockIdx.x * blockDim.x + threadIdx.x;
    int lane  = threadIdx.x & 63;
    int wave  = gtid >> 6;
    int nwaves = (gridDim.x * blockDim.x) >> 6;
    for (int q = wave; q < ntot; q += nwaves) {
        const float* src; uint64_t* dst; int qi;
        if (q < nx) { src = x; dst = xp; qi = q; }
        else        { src = w; dst = wp; qi = q - nx; }
        float v = src[(size_t)qi * 64 + lane];
        unsigned long long m = __ballot(v < 0.0f);
        if (lane == 0) dst[qi] = (uint64_t)m;
    }
}

__global__ __launch_bounds__(512, 2) void bgemm_popc_fb(
        const uint64_t* __restrict__ xp, const uint64_t* __restrict__ wp,
        const float* __restrict__ bias, float* __restrict__ out)
{
    __shared__ uint64_t xs[128 * LSTRIDE];
    __shared__ uint64_t ws[128 * LSTRIDE];
    const int tid  = threadIdx.x;
    const int row0 = blockIdx.y * 128;
    const int col0 = blockIdx.x * 128;
    {
        const uint64_t* xg = xp + (size_t)row0 * KW;
        const uint64_t* wg = wp + (size_t)col0 * KW;
#pragma unroll
        for (int m = 0; m < 8; ++m) {
            int q = (m * 512 + tid) * 2;
            int r = q >> 6;
            int k = q & 63;
            ulonglong2 vx = *reinterpret_cast<const ulonglong2*>(xg + q);
            xs[r * LSTRIDE + k] = vx.x; xs[r * LSTRIDE + k + 1] = vx.y;
            ulonglong2 vw = *reinterpret_cast<const ulonglong2*>(wg + q);
            ws[r * LSTRIDE + k] = vw.x; ws[r * LSTRIDE + k + 1] = vw.y;
        }
    }
    __syncthreads();
    const int tx = tid & 15;
    const int ty = tid >> 4;
    int acc[4][8];
#pragma unroll
    for (int i = 0; i < 4; ++i)
#pragma unroll
        for (int j = 0; j < 8; ++j) acc[i][j] = 0;
    const uint64_t* xrow = xs + ty * 4 * LSTRIDE;
    const uint64_t* wrow = ws + tx * LSTRIDE;
#pragma unroll 4
    for (int kk = 0; kk < KW; kk += 2) {
        ulonglong2 a[4]; ulonglong2 b[8];
#pragma unroll
        for (int i = 0; i < 4; ++i)
            a[i] = *reinterpret_cast<const ulonglong2*>(xrow + i * LSTRIDE + kk);
#pragma unroll
        for (int j = 0; j < 8; ++j)
            b[j] = *reinterpret_cast<const ulonglong2*>(wrow + j * 16 * LSTRIDE + kk);
#pragma unroll
        for (int i = 0; i < 4; ++i)
#pragma unroll
            for (int j = 0; j < 8; ++j)
                acc[i][j] += __builtin_popcountll(a[i].x ^ b[j].x)
                           + __builtin_popcountll(a[i].y ^ b[j].y);
    }
    float bcol[8];
#pragma unroll
    for (int j = 0; j < 8; ++j) bcol[j] = bias[col0 + tx + 16 * j];
#pragma unroll
    for (int i = 0; i < 4; ++i) {
        size_t r = (size_t)(row0 + ty * 4 + i);
#pragma unroll
        for (int j = 0; j < 8; ++j) {
            int c = col0 + tx + 16 * j;
            out[r * OUTF + c] = (float)(INF - 2 * acc[i][j]) + bcol[j];
        }
    }
}
// ============================================================================

extern "C" void kernel_launch(void* const* d_in, const int* in_sizes, int n_in,
                              void* d_out, int out_size, void* d_ws, size_t ws_size,
                              hipStream_t stream) {
    const float* x    = (const float*)d_in[0];
    const float* w    = (const float*)d_in[1];
    const float* bias = (const float*)d_in[2];
    float* out = (float*)d_out;

    const size_t need4 = (size_t)NTOK * KB4 + (size_t)OUTF * KB4;   // 25.2 MB
    const size_t need8 = (size_t)NTOK * KDIM + (size_t)OUTF * KDIM; // 50.3 MB

    if (ws_size >= need4) {
        char* xp = (char*)d_ws;
        char* wp = xp + (size_t)NTOK * KB4;
        const int gx   = NTOK * KDIM / 16;                // 2097152 (16-float tasks)
        const int gtot = gx + OUTF * KDIM / 16;           // 3145728
        pack_fp4<<<2048, 256, 0, stream>>>(x, w, xp, wp, gx, gtot);
        bgemm_fp4<<<512, 512, 0, stream>>>(xp, wp, bias, out);
    } else if (ws_size >= need8) {
        char* xp = (char*)d_ws;
        char* wp = xp + (size_t)NTOK * KDIM;
        const int gx   = NTOK * KDIM / 16;
        const int gtot = gx + OUTF * KDIM / 16;
        pack_i8<<<2048, 256, 0, stream>>>(x, w, xp, wp, gx, gtot);
        bgemm_i8_4ph<<<512, 512, 0, stream>>>(xp, wp, bias, out);
    } else {
        uint64_t* xp = (uint64_t*)d_ws;
        uint64_t* wp = xp + (size_t)NTOK * KW;
        const int nx   = NTOK * KW;
        const int ntot = nx + OUTF * KW;
        pack_both_fb<<<2048, 256, 0, stream>>>(x, w, xp, wp, nx, ntot);
        dim3 grid(OUTF / 128, NTOK / 128);
        bgemm_popc_fb<<<grid, 512, 0, stream>>>(xp, wp, bias, out);
    }
}

// Round 17
// 120.645 us; speedup vs baseline: 1.0966x; 1.0009x over previous
//
#include <hip/hip_runtime.h>
#include <stdint.h>

#define NTOK 8192
#define INF  4096
#define OUTF 4096
#define KDIM 4096
#define KB4  2048   // packed fp4 row bytes (2 elems/byte)
#define EPI_STRIDE 260  // epilogue LDS row stride in floats (1040B, 16B-aligned; breaks 4-way bank conflict)

using i32x4 = __attribute__((ext_vector_type(4))) int;
using i32x8 = __attribute__((ext_vector_type(8))) int;
using f32x4 = __attribute__((ext_vector_type(4))) float;

#define GLOAD16(gp, lp) __builtin_amdgcn_global_load_lds( \
    (const __attribute__((address_space(1))) uint32_t*)(gp), \
    (__attribute__((address_space(3))) uint32_t*)(lp), 16, 0, 0)

#define SBARE()  do { __builtin_amdgcn_s_barrier(); __builtin_amdgcn_sched_barrier(0); } while (0)
#define VMCNT4() do { asm volatile("s_waitcnt vmcnt(4)" ::: "memory"); __builtin_amdgcn_sched_barrier(0); } while (0)
#define VMCNT0() do { asm volatile("s_waitcnt vmcnt(0)" ::: "memory"); __builtin_amdgcn_sched_barrier(0); } while (0)

// full-grid XCD swizzle (512 blocks, 8 XCDs)
__device__ __forceinline__ void full_swizzle(int orig, int& row0, int& col0) {
    const int wgid  = ((orig & 7) << 6) | (orig >> 3);
    const int chunk = wgid >> 6;
    const int c     = wgid & 63;
    row0 = ((chunk << 2) | (c & 3)) * 256;
    col0 = (c >> 2) * 256;
}

// ---------------- pack pass v4: 16 floats/thread, 4 loads in flight ---------
__device__ __forceinline__ unsigned int nib16(float4 v) {
    return (0x2u | ((v.x < 0.0f) ? 8u : 0u))
         | ((0x2u | ((v.y < 0.0f) ? 8u : 0u)) << 4)
         | ((0x2u | ((v.z < 0.0f) ? 8u : 0u)) << 8)
         | ((0x2u | ((v.w < 0.0f) ? 8u : 0u)) << 12);
}

__global__ void pack_fp4(const float* __restrict__ x, const float* __restrict__ w,
                         char* __restrict__ xp, char* __restrict__ wp,
                         int gx, int gtot) {
    int gtid = blockIdx.x * blockDim.x + threadIdx.x;
    int nthr = gridDim.x * blockDim.x;
    for (int g = gtid; g < gtot; g += nthr) {
        const float4* s;
        uint64_t* d;
        int gi;
        if (g < gx) { s = (const float4*)x; d = (uint64_t*)xp; gi = g; }
        else        { s = (const float4*)w; d = (uint64_t*)wp; gi = g - gx; }
        const float4* sp = s + (size_t)gi * 4;
        float4 v0 = sp[0];
        float4 v1 = sp[1];
        float4 v2 = sp[2];
        float4 v3 = sp[3];
        uint32_t lo = nib16(v0) | (nib16(v1) << 16);
        uint32_t hi = nib16(v2) | (nib16(v3) << 16);
        d[gi] = (uint64_t)lo | ((uint64_t)hi << 32);
    }
}

// ---------------- MX-FP4 MFMA GEMM, 256x256, 4-phase + LDS-transpose epi ----
// Compute/schedule = R13-proven core (absmax 0). Epilogue: acc -> LDS (row
// stride 260 floats: 4r%32 spreads rg-groups across banks -> 2-way aliasing,
// free) -> f32x4/lane read-back -> nontemporal full-line stores. Output
// bypasses L3; x,w stay L3-resident for pack (confirmed R16: pack 78->31us).
__global__ __launch_bounds__(512, 2) void bgemm_fp4(
        const char*  __restrict__ Xp,   // [NTOK][KB4] fp4-packed signs
        const char*  __restrict__ Wp,   // [OUTF][KB4]
        const float* __restrict__ bias, // [OUTF]
        float*       __restrict__ out)  // [NTOK][OUTF]
{
    __shared__ __align__(16) char smem[128 * EPI_STRIDE * 4];  // 133120 B >= 131072 for A/B tiles
#define ASm(p) (smem + ((p) << 15))
#define BSm(p) (smem + 65536 + ((p) << 15))

    const int tid  = threadIdx.x;
    const int lane = tid & 63;
    const int wid  = tid >> 6;
    const int wr   = wid >> 2;          // 0..1 (128-row half)
    const int wc   = wid & 3;           // 0..3 (64-col quarter)
    const int cl   = lane & 15;
    const int rg   = lane >> 4;

    int row0, col0;
    full_swizzle(blockIdx.x, row0, col0);

    const int rr     = tid >> 3;                       // 0..63
    const int colOff = ((tid & 7) << 4) ^ ((rr & 7) << 4);
    const char* gA = Xp + (size_t)(row0 + rr) * KB4 + colOff;
    const char* gB = Wp + (size_t)(col0 + rr) * KB4 + colOff;
    const int d0 = tid * 16;

#define STGF(base, g, ktB) do { \
    GLOAD16((g) + (size_t)0   * KB4 + (ktB), (base) + d0); \
    GLOAD16((g) + (size_t)64  * KB4 + (ktB), (base) + 8192 + d0); \
    GLOAD16((g) + (size_t)128 * KB4 + (ktB), (base) + 16384 + d0); \
    GLOAD16((g) + (size_t)192 * KB4 + (ktB), (base) + 24576 + d0); \
} while (0)

    const int aRow = (wr * 128 + cl) * 128;
    const int bRow = (wc * 64 + cl) * 128;
    const int kq0  = (rg << 4) ^ ((cl & 7) << 4);
    const int kq1  = kq0 ^ 64;

    f32x4 acc[8][4];
#pragma unroll
    for (int m = 0; m < 8; ++m)
#pragma unroll
        for (int n = 0; n < 4; ++n)
#pragma unroll
            for (int j = 0; j < 4; ++j) acc[m][n][j] = 0.0f;

    i32x4 af[4][2], bf[4][2];

#define LDA(p, MH) do { \
    _Pragma("unroll") for (int m = 0; m < 4; ++m) { \
        af[m][0] = *reinterpret_cast<const i32x4*>(ASm(p) + aRow + ((MH) * 4 + m) * 2048 + kq0); \
        af[m][1] = *reinterpret_cast<const i32x4*>(ASm(p) + aRow + ((MH) * 4 + m) * 2048 + kq1); \
    } } while (0)
#define LDBALL(p) do { \
    _Pragma("unroll") for (int n = 0; n < 4; ++n) { \
        bf[n][0] = *reinterpret_cast<const i32x4*>(BSm(p) + bRow + (n) * 2048 + kq0); \
        bf[n][1] = *reinterpret_cast<const i32x4*>(BSm(p) + bRow + (n) * 2048 + kq1); \
    } } while (0)
// kk outer so consecutive MFMAs hit different acc registers.
#define MMALL(MH) do { \
    __builtin_amdgcn_s_setprio(1); \
    _Pragma("unroll") for (int kk = 0; kk < 2; ++kk) \
    _Pragma("unroll") for (int m = 0; m < 4; ++m) \
    _Pragma("unroll") for (int n = 0; n < 4; ++n) { \
        i32x8 a8 = {af[m][kk][0], af[m][kk][1], af[m][kk][2], af[m][kk][3], 0, 0, 0, 0}; \
        i32x8 b8 = {bf[n][kk][0], bf[n][kk][1], bf[n][kk][2], bf[n][kk][3], 0, 0, 0, 0}; \
        acc[(MH) * 4 + m][n] = __builtin_amdgcn_mfma_scale_f32_16x16x128_f8f6f4( \
            a8, b8, acc[(MH) * 4 + m][n], 4, 4, 0, 0x7F7F7F7F, 0, 0x7F7F7F7F); \
    } \
    __builtin_amdgcn_s_setprio(0); \
} while (0)

    // ---- prologue: tile0 (A,B) + tile1 B = 12 gloads; retire tile0 --------
    STGF(ASm(0), gA, 0);
    STGF(BSm(0), gB, 0);
    STGF(BSm(1), gB, 128);
    VMCNT4();
    SBARE();

    // ---- main loop: tile 2i (p0) ph0-1, tile 2i+1 (p1) ph2-3 --------------
    int kb = 0;  // = i*256 bytes
#pragma unroll 1
    for (int i = 0; i < 7; ++i, kb += 256) {
        // ph0: reads A(p0,MH0)+B(p0) ; stage A.p1(t+1) ; MFMA(MH0)
        LDA(0, 0); LDBALL(0);
        STGF(ASm(1), gA, kb + 128);
        MMALL(0);
        SBARE();
        // ph1: reads A(p0,MH1) ; stage B.p0(t+2) ; MFMA(MH1) ; vmcnt(4)
        LDA(0, 1);
        STGF(BSm(0), gB, kb + 256);
        MMALL(1);
        VMCNT4(); SBARE();
        // ph2: reads A(p1,MH0)+B(p1) ; stage A.p0(t+2) ; MFMA(MH0)
        LDA(1, 0); LDBALL(1);
        STGF(ASm(0), gA, kb + 256);
        MMALL(0);
        SBARE();
        // ph3: reads A(p1,MH1) ; stage B.p1(t+3) ; MFMA(MH1) ; vmcnt(4)
        LDA(1, 1);
        STGF(BSm(1), gB, kb + 384);
        MMALL(1);
        VMCNT4(); SBARE();
    }

    // ---- K-epilogue: stage A.p1 (tile15 @1920); drain; compute t14, t15 ---
    STGF(ASm(1), gA, 1920);
    VMCNT0();
    SBARE();
    LDA(0, 0); LDBALL(0); MMALL(0);
    LDA(0, 1);            MMALL(1);
    LDA(1, 0); LDBALL(1); MMALL(0);
    LDA(1, 1);            MMALL(1);

    // ---- C-epilogue: acc -> LDS (stride 260) -> f32x4 nt full-line stores -
    __syncthreads();
    float* lds_c = (float*)smem;        // 128 rows x EPI_STRIDE floats

    float bv[4];
#pragma unroll
    for (int n = 0; n < 4; ++n) bv[n] = bias[col0 + wc * 64 + n * 16 + cl];

#pragma unroll 1
    for (int ch = 0; ch < 2; ++ch) {
        if (wr == ch) {                 // waves owning rows [ch*128, ch*128+128)
#pragma unroll
            for (int m = 0; m < 8; ++m)
#pragma unroll
                for (int j = 0; j < 4; ++j) {
                    int r = m * 16 + rg * 4 + j;
#pragma unroll
                    for (int n = 0; n < 4; ++n)
                        lds_c[r * EPI_STRIDE + wc * 64 + n * 16 + cl] = acc[m][n][j] + bv[n];
                }
        }
        __syncthreads();
        // read back: wave covers one full 1KB output row per instruction
#pragma unroll
        for (int i = 0; i < 16; ++i) {
            int r = wid * 16 + i;
            f32x4 v = *reinterpret_cast<const f32x4*>(&lds_c[r * EPI_STRIDE + lane * 4]);
            size_t grow = (size_t)(row0 + ch * 128 + r);
            __builtin_nontemporal_store(v,
                reinterpret_cast<f32x4*>(&out[grow * OUTF + col0 + lane * 4]));
        }
        if (ch == 0) __syncthreads();   // guard lds_c reuse; final sync unneeded
    }
#undef STGF
#undef LDA
#undef LDBALL
#undef MMALL
#undef ASm
#undef BSm
}

// ================= i8 path (R7 core, verified) — ws fallback ================
__global__ void pack_i8(const float* __restrict__ x, const float* __restrict__ w,
                        char* __restrict__ xp, char* __restrict__ wp,
                        int gx, int gtot) {
    int gtid = blockIdx.x * blockDim.x + threadIdx.x;
    int nthr = gridDim.x * blockDim.x;
    for (int g = gtid; g < gtot; g += nthr) {
        const float* src;
        char* dst;
        int gi;
        if (g < gx) { src = x; dst = xp; gi = g; }
        else        { src = w; dst = wp; gi = g - gx; }
        const float4* s4 = reinterpret_cast<const float4*>(src + (size_t)gi * 16);
        int words[4];
#pragma unroll
        for (int q = 0; q < 4; ++q) {
            float4 v = s4[q];
            int b0 = (v.x < 0.0f) ? 0xFF : 0x01;
            int b1 = (v.y < 0.0f) ? 0xFF : 0x01;
            int b2 = (v.z < 0.0f) ? 0xFF : 0x01;
            int b3 = (v.w < 0.0f) ? 0xFF : 0x01;
            words[q] = b0 | (b1 << 8) | (b2 << 16) | (b3 << 24);
        }
        int4 o = make_int4(words[0], words[1], words[2], words[3]);
        *reinterpret_cast<int4*>(dst + (size_t)gi * 16) = o;
    }
}

__global__ __launch_bounds__(512, 2) void bgemm_i8_4ph(
        const char*  __restrict__ Xp, const char* __restrict__ Wp,
        const float* __restrict__ bias, float* __restrict__ out)
{
    __shared__ __align__(16) char As[2][32768];
    __shared__ __align__(16) char Bs[2][32768];

    const int tid  = threadIdx.x;
    const int lane = tid & 63;
    const int wid  = tid >> 6;
    const int wr   = wid >> 2;
    const int wc   = wid & 3;
    const int cl   = lane & 15;
    const int rg   = lane >> 4;

    int row0, col0;
    full_swizzle(blockIdx.x, row0, col0);

    const int rr     = tid >> 3;
    const int colOff = ((tid & 7) << 4) ^ ((rr & 7) << 4);
    const char* gA = Xp + (size_t)(row0 + rr) * KDIM + colOff;
    const char* gB = Wp + (size_t)(col0 + rr) * KDIM + colOff;
    const int d0 = tid * 16;

#define STGF(arr, p, g, ktB) do { \
    GLOAD16((g) + (size_t)0   * KDIM + (ktB), &arr[p][d0]); \
    GLOAD16((g) + (size_t)64  * KDIM + (ktB), &arr[p][8192 + d0]); \
    GLOAD16((g) + (size_t)128 * KDIM + (ktB), &arr[p][16384 + d0]); \
    GLOAD16((g) + (size_t)192 * KDIM + (ktB), &arr[p][24576 + d0]); \
} while (0)

    const int aRow = (wr * 128 + cl) * 128;
    const int bRow = (wc * 64 + cl) * 128;
    const int kq0  = (rg << 4) ^ ((cl & 7) << 4);
    const int kq1  = kq0 ^ 64;

    i32x4 acc[8][4];
#pragma unroll
    for (int m = 0; m < 8; ++m)
#pragma unroll
        for (int n = 0; n < 4; ++n)
#pragma unroll
            for (int j = 0; j < 4; ++j) acc[m][n][j] = 0;

    i32x4 af[4][2], bf[4][2];

#define LDA(p, MH) do { \
    _Pragma("unroll") for (int m = 0; m < 4; ++m) { \
        af[m][0] = *reinterpret_cast<const i32x4*>(&As[p][aRow + ((MH) * 4 + m) * 2048 + kq0]); \
        af[m][1] = *reinterpret_cast<const i32x4*>(&As[p][aRow + ((MH) * 4 + m) * 2048 + kq1]); \
    } } while (0)
#define LDBALL(p) do { \
    _Pragma("unroll") for (int n = 0; n < 4; ++n) { \
        bf[n][0] = *reinterpret_cast<const i32x4*>(&Bs[p][bRow + (n) * 2048 + kq0]); \
        bf[n][1] = *reinterpret_cast<const i32x4*>(&Bs[p][bRow + (n) * 2048 + kq1]); \
    } } while (0)
#define MMALL(MH) do { \
    __builtin_amdgcn_s_setprio(1); \
    _Pragma("unroll") for (int m = 0; m < 4; ++m) \
    _Pragma("unroll") for (int n = 0; n < 4; ++n) \
    _Pragma("unroll") for (int kk = 0; kk < 2; ++kk) \
        acc[(MH) * 4 + m][n] = __builtin_amdgcn_mfma_i32_16x16x64_i8( \
            af[m][kk], bf[n][kk], acc[(MH) * 4 + m][n], 0, 0, 0); \
    __builtin_amdgcn_s_setprio(0); \
} while (0)

    STGF(As, 0, gA, 0);
    STGF(Bs, 0, gB, 0);
    STGF(Bs, 1, gB, 128);
    VMCNT4();
    SBARE();

    int kb = 0;
#pragma unroll 1
    for (int i = 0; i < 15; ++i, kb += 256) {
        LDA(0, 0); LDBALL(0);
        STGF(As, 1, gA, kb + 128);
        MMALL(0);
        SBARE();
        LDA(0, 1);
        STGF(Bs, 0, gB, kb + 256);
        MMALL(1);
        VMCNT4(); SBARE();
        LDA(1, 0); LDBALL(1);
        STGF(As, 0, gA, kb + 256);
        MMALL(0);
        SBARE();
        LDA(1, 1);
        STGF(Bs, 1, gB, kb + 384);
        MMALL(1);
        VMCNT4(); SBARE();
    }

    STGF(As, 1, gA, 3968);
    VMCNT0();
    SBARE();
    LDA(0, 0); LDBALL(0); MMALL(0);
    LDA(0, 1);            MMALL(1);
    LDA(1, 0); LDBALL(1); MMALL(0);
    LDA(1, 1);            MMALL(1);

    float bv[4];
#pragma unroll
    for (int n = 0; n < 4; ++n) bv[n] = bias[col0 + wc * 64 + n * 16 + cl];

#pragma unroll
    for (int m = 0; m < 8; ++m) {
        int rowbase = row0 + wr * 128 + m * 16 + rg * 4;
#pragma unroll
        for (int j = 0; j < 4; ++j) {
            size_t rb = (size_t)(rowbase + j) * OUTF;
#pragma unroll
            for (int n = 0; n < 4; ++n) {
                int col = col0 + wc * 64 + n * 16 + cl;
                out[rb + col] = (float)acc[m][n][j] + bv[n];
            }
        }
    }
#undef STGF
#undef LDA
#undef LDBALL
#undef MMALL
}

// ================= popcount fallback (round-1, known-good) ==================
#define KW   64
#define LSTRIDE 66

__global__ void pack_both_fb(const float* __restrict__ x, const float* __restrict__ w,
                             uint64_t* __restrict__ xp, uint64_t* __restrict__ wp,
                             int nx, int ntot) {
    int gtid  = blockIdx.x * blockDim.x + threadIdx.x;
    int lane  = threadIdx.x & 63;
    int wave  = gtid >> 6;
    int nwaves = (gridDim.x * blockDim.x) >> 6;
    for (int q = wave; q < ntot; q += nwaves) {
        const float* src; uint64_t* dst; int qi;
        if (q < nx) { src = x; dst = xp; qi = q; }
        else        { src = w; dst = wp; qi = q - nx; }
        float v = src[(size_t)qi * 64 + lane];
        unsigned long long m = __ballot(v < 0.0f);
        if (lane == 0) dst[qi] = (uint64_t)m;
    }
}

__global__ __launch_bounds__(512, 2) void bgemm_popc_fb(
        const uint64_t* __restrict__ xp, const uint64_t* __restrict__ wp,
        const float* __restrict__ bias, float* __restrict__ out)
{
    __shared__ uint64_t xs[128 * LSTRIDE];
    __shared__ uint64_t ws[128 * LSTRIDE];
    const int tid  = threadIdx.x;
    const int row0 = blockIdx.y * 128;
    const int col0 = blockIdx.x * 128;
    {
        const uint64_t* xg = xp + (size_t)row0 * KW;
        const uint64_t* wg = wp + (size_t)col0 * KW;
#pragma unroll
        for (int m = 0; m < 8; ++m) {
            int q = (m * 512 + tid) * 2;
            int r = q >> 6;
            int k = q & 63;
            ulonglong2 vx = *reinterpret_cast<const ulonglong2*>(xg + q);
            xs[r * LSTRIDE + k] = vx.x; xs[r * LSTRIDE + k + 1] = vx.y;
            ulonglong2 vw = *reinterpret_cast<const ulonglong2*>(wg + q);
            ws[r * LSTRIDE + k] = vw.x; ws[r * LSTRIDE + k + 1] = vw.y;
        }
    }
    __syncthreads();
    const int tx = tid & 15;
    const int ty = tid >> 4;
    int acc[4][8];
#pragma unroll
    for (int i = 0; i < 4; ++i)
#pragma unroll
        for (int j = 0; j < 8; ++j) acc[i][j] = 0;
    const uint64_t* xrow = xs + ty * 4 * LSTRIDE;
    const uint64_t* wrow = ws + tx * LSTRIDE;
#pragma unroll 4
    for (int kk = 0; kk < KW; kk += 2) {
        ulonglong2 a[4]; ulonglong2 b[8];
#pragma unroll
        for (int i = 0; i < 4; ++i)
            a[i] = *reinterpret_cast<const ulonglong2*>(xrow + i * LSTRIDE + kk);
#pragma unroll
        for (int j = 0; j < 8; ++j)
            b[j] = *reinterpret_cast<const ulonglong2*>(wrow + j * 16 * LSTRIDE + kk);
#pragma unroll
        for (int i = 0; i < 4; ++i)
#pragma unroll
            for (int j = 0; j < 8; ++j)
                acc[i][j] += __builtin_popcountll(a[i].x ^ b[j].x)
                           + __builtin_popcountll(a[i].y ^ b[j].y);
    }
    float bcol[8];
#pragma unroll
    for (int j = 0; j < 8; ++j) bcol[j] = bias[col0 + tx + 16 * j];
#pragma unroll
    for (int i = 0; i < 4; ++i) {
        size_t r = (size_t)(row0 + ty * 4 + i);
#pragma unroll
        for (int j = 0; j < 8; ++j) {
            int c = col0 + tx + 16 * j;
            out[r * OUTF + c] = (float)(INF - 2 * acc[i][j]) + bcol[j];
        }
    }
}
// ============================================================================

extern "C" void kernel_launch(void* const* d_in, const int* in_sizes, int n_in,
                              void* d_out, int out_size, void* d_ws, size_t ws_size,
                              hipStream_t stream) {
    const float* x    = (const float*)d_in[0];
    const float* w    = (const float*)d_in[1];
    const float* bias = (const float*)d_in[2];
    float* out = (float*)d_out;

    const size_t need4 = (size_t)NTOK * KB4 + (size_t)OUTF * KB4;   // 25.2 MB
    const size_t need8 = (size_t)NTOK * KDIM + (size_t)OUTF * KDIM; // 50.3 MB

    if (ws_size >= need4) {
        char* xp = (char*)d_ws;
        char* wp = xp + (size_t)NTOK * KB4;
        const int gx   = NTOK * KDIM / 16;                // 2097152 (16-float tasks)
        const int gtot = gx + OUTF * KDIM / 16;           // 3145728
        pack_fp4<<<2048, 256, 0, stream>>>(x, w, xp, wp, gx, gtot);
        bgemm_fp4<<<512, 512, 0, stream>>>(xp, wp, bias, out);
    } else if (ws_size >= need8) {
        char* xp = (char*)d_ws;
        char* wp = xp + (size_t)NTOK * KDIM;
        const int gx   = NTOK * KDIM / 16;
        const int gtot = gx + OUTF * KDIM / 16;
        pack_i8<<<2048, 256, 0, stream>>>(x, w, xp, wp, gx, gtot);
        bgemm_i8_4ph<<<512, 512, 0, stream>>>(xp, wp, bias, out);
    } else {
        uint64_t* xp = (uint64_t*)d_ws;
        uint64_t* wp = xp + (size_t)NTOK * KW;
        const int nx   = NTOK * KW;
        const int ntot = nx + OUTF * KW;
        pack_both_fb<<<2048, 256, 0, stream>>>(x, w, xp, wp, nx, ntot);
        dim3 grid(OUTF / 128, NTOK / 128);
        bgemm_popc_fb<<<grid, 512, 0, stream>>>(xp, wp, bias, out);
    }
}